// Round 4
// baseline (2631.020 us; speedup 1.0000x reference)
//
#include <hip/hip_runtime.h>
#include <math.h>
#include <stdint.h>

// Shapes (fixed by the reference)
// N=10000, E=100000, G=64, NB=16, EMB=16, S=8, COUT=16, LMAX=2
// WNUM = 3*16*8*8 = 3072 ; ef width = 16 + 48 + 144 = 208
// Per-edge compact result: m[48] (l*16+o) + n[3], stored as 52 floats.

__device__ __forceinline__ float silu_f(float x) {
    return x / (1.0f + __expf(-x));
}

// Force a (wave-uniform) pointer into VGPRs so subsequent loads become
// global_load (VMEM broadcast, vmcnt-pipelined) instead of s_load (K$ +
// lgkmcnt(0) drains that serialize against ds_read).
__device__ __forceinline__ const float* make_divergent(const float* p) {
    uint64_t in = (uint64_t)p;
    uint32_t lo = (uint32_t)in, hi = (uint32_t)(in >> 32);
    uint32_t vlo, vhi;
    asm volatile("v_mov_b32 %0, %2\n\tv_mov_b32 %1, %3"
                 : "=v"(vlo), "=v"(vhi)
                 : "s"(lo), "s"(hi));
    return (const float*)(((uint64_t)vhi << 32) | (uint64_t)vlo);
}

// ---------------- kernel 1: relayout fc_w3 (64c x 3072) -> w3T2[ab][lo][c], b3 -> b3T[ab][lo] ----------------
__global__ __launch_bounds__(256) void k_transpose_w3(const float* __restrict__ w3,
                                                      const float* __restrict__ b3,
                                                      float* __restrict__ w3T2,
                                                      float* __restrict__ b3T) {
    int t = blockIdx.x * 256 + threadIdx.x;       // t = (ab*48 + lo)*64 + c
    if (t >= 64 * 48 * 64) return;
    int c  = t & 63;
    int v  = t >> 6;          // ab*48 + lo
    int lo = v % 48;
    int ab = v / 48;
    w3T2[t] = w3[c * 3072 + lo * 64 + ab];
    if (t < 64 * 48) {
        int lo2 = t % 48, ab2 = t / 48;
        b3T[t] = b3[lo2 * 64 + ab2];
    }
}

// ---------------- kernel 2: per-node Ai ----------------
__global__ __launch_bounds__(256) void k_node_ai(const int* __restrict__ A,
                                                 const float* __restrict__ embt,
                                                 const float* __restrict__ w1,
                                                 const float* __restrict__ b1,
                                                 const float* __restrict__ w2,
                                                 const float* __restrict__ b2,
                                                 float* __restrict__ Ai, int N) {
    int i = blockIdx.x * 256 + threadIdx.x;
    if (i >= N) return;
    float e[16];
    const float* er = embt + A[i] * 16;
    #pragma unroll
    for (int k = 0; k < 16; ++k) e[k] = er[k];
    float h1[64];
    #pragma unroll
    for (int j = 0; j < 64; ++j) {
        float a = b1[j];
        #pragma unroll
        for (int k = 0; k < 16; ++k) a = fmaf(e[k], w1[k * 64 + j], a);
        h1[j] = silu_f(a);
    }
    #pragma unroll
    for (int o = 0; o < 8; ++o) {
        float a = b2[o];
        #pragma unroll
        for (int j = 0; j < 64; ++j) a = fmaf(h1[j], w2[j * 8 + o], a);
        Ai[i * 8 + o] = a;
    }
}

// ---------------- kernel 3: histogram of edge_dst ----------------
__global__ __launch_bounds__(256) void k_hist(const int* __restrict__ edst,
                                              int* __restrict__ deg, int E) {
    int e = blockIdx.x * 256 + threadIdx.x;
    if (e < E) atomicAdd(&deg[edst[e]], 1);
}

// ---------------- kernel 4: single-block exclusive scan (N=10000) ----------------
__global__ __launch_bounds__(256) void k_scan(const int* __restrict__ deg,
                                              int* __restrict__ offs,
                                              int* __restrict__ cursor, int N) {
    __shared__ int part[256];
    const int t = threadIdx.x;
    const int chunk = (N + 255) / 256;
    const int beg = t * chunk;
    const int end = min(beg + chunk, N);
    int s = 0;
    for (int i = beg; i < end; ++i) s += deg[i];
    part[t] = s;
    __syncthreads();
    for (int off = 1; off < 256; off <<= 1) {
        int v = (t >= off) ? part[t - off] : 0;
        __syncthreads();
        part[t] += v;
        __syncthreads();
    }
    int run = (t == 0) ? 0 : part[t - 1];
    for (int i = beg; i < end; ++i) {
        offs[i] = run;
        cursor[i] = run;
        run += deg[i];
    }
    if (t == 255) offs[N] = part[255];
}

// ---------------- kernel 5: per-edge compute ----------------
// Block = 256 threads = 4 waves, 64 edges (lane = edge slot).
// Wave p owns c-chunk [16p,16p+16). ab is the OUTER runtime loop; all 48 lo
// accumulate in registers (macc[48], fully unrolled -> static indices).
// w3/b3 streams: VMEM broadcast loads (divergent-forced pointer), so the hot
// loop has zero scalar loads and one prefetched ds_read per ab.
__global__ __launch_bounds__(256, 2) void k_edge(
    const float* __restrict__ pos, const int* __restrict__ batch,
    const int* __restrict__ esrc, const int* __restrict__ edst,
    const float* __restrict__ eshift, const float* __restrict__ cell,
    const float* __restrict__ fw1, const float* __restrict__ fb1,
    const float* __restrict__ fw2, const float* __restrict__ fb2,
    const float* __restrict__ w3T2, const float* __restrict__ b3T,
    const float* __restrict__ Ai, float* __restrict__ ef,
    int* __restrict__ cursor, int* __restrict__ eidx, int E) {

    // s_buf: first h1[64 edges][65-pad], then mpart[4 waves][64 edges][17-pad].
    __shared__ float s_buf[4 * 64 * 17];     // 17408 B
    __shared__ float s_o[64 * 65];           // o[e][ab], pad 65 -> conflict-free

    const int tid  = threadIdx.x;
    const int lane = tid & 63;                                   // edge slot
    const int p    = __builtin_amdgcn_readfirstlane(tid >> 6);   // wave id = c-chunk
    const int e0   = blockIdx.x * 64;
    const int e    = e0 + lane;
    const bool valid = (e < E);
    const int ec   = valid ? e : (E - 1);    // clamped index for safe loads

    const int src = esrc[ec];
    const int dst = edst[ec];

    // ---- geometry ----
    const int g = batch[src];
    const float s0 = eshift[ec * 3 + 0], s1 = eshift[ec * 3 + 1], s2 = eshift[ec * 3 + 2];
    const float* cl = cell + g * 9;
    float vx = pos[dst * 3 + 0] - pos[src * 3 + 0] + s0 * cl[0] + s1 * cl[3] + s2 * cl[6];
    float vy = pos[dst * 3 + 1] - pos[src * 3 + 1] + s0 * cl[1] + s1 * cl[4] + s2 * cl[7];
    float vz = pos[dst * 3 + 2] - pos[src * 3 + 2] + s0 * cl[2] + s1 * cl[5] + s2 * cl[8];
    float r = sqrtf(vx * vx + vy * vy + vz * vz);
    float rinv = 1.0f / fmaxf(r, 1e-9f);
    float nx = vx * rinv, ny = vy * rinv, nz = vz * rinv;

    // ---- radial basis (NB=16) ----
    float embv[16];
    const float step = 4.0f / 17.0f;
    const float sc = 4.0f / 1.12f;
    #pragma unroll
    for (int k = 0; k < 16; ++k) {
        float d = (r - (float)(k + 1) * step) / step;
        embv[k] = __expf(-d * d) * sc;
    }

    // ---- h1 chunk -> LDS: wave p computes h1[j], j in [16p,16p+16) ----
    const int j0 = p * 16;
    #pragma unroll
    for (int jj = 0; jj < 16; ++jj) {
        const int j = j0 + jj;
        float a = fb1[j];
        #pragma unroll
        for (int k = 0; k < 16; ++k) a = fmaf(embv[k], fw1[k * 64 + j], a);
        s_buf[lane * 65 + j] = silu_f(a);
    }

    // ---- o chunk -> LDS: wave p computes o[ab], ab in [16p,16p+16) ----
    {
        const float* As = Ai + (size_t)src * 8;
        const float* Ad = Ai + (size_t)dst * 8;
        float fsa0 = As[2 * p], fsa1 = As[2 * p + 1];
        float4 d0 = *reinterpret_cast<const float4*>(Ad);
        float4 d1 = *reinterpret_cast<const float4*>(Ad + 4);
        float fdv[8] = {d0.x, d0.y, d0.z, d0.w, d1.x, d1.y, d1.z, d1.w};
        const int ob = lane * 65 + j0;
        #pragma unroll
        for (int i = 0; i < 8; ++i)  s_o[ob + i]     = fsa0 * fdv[i];
        #pragma unroll
        for (int i = 0; i < 8; ++i)  s_o[ob + 8 + i] = fsa1 * fdv[i];
    }
    __syncthreads();   // h1 + o fully written

    // ---- hc chunk (registers): h[c], c in [16p,16p+16) ----
    float hc[16];
    #pragma unroll
    for (int i = 0; i < 16; ++i) hc[i] = fb2[j0 + i];
    #pragma unroll 4
    for (int j = 0; j < 64; ++j) {
        const float v = s_buf[lane * 65 + j];
        const float* w2r = fw2 + j * 64 + j0;   // wave-uniform -> scalar (small)
        #pragma unroll
        for (int i = 0; i < 16; ++i) hc[i] = fmaf(v, w2r[i], hc[i]);
    }
    #pragma unroll
    for (int i = 0; i < 16; ++i) hc[i] = silu_f(hc[i]);
    __syncthreads();   // s_buf free -> becomes mpart

    // ---- main contraction: ab outer (runtime), lo inner (unrolled) ----
    // partial m[lo] = sum_ab (0.25*b3T[ab][lo] + sum_{c chunk} hc*w3T2[ab][lo][c]) * o[ab]
    const float* wab = make_divergent(w3T2 + j0);   // VGPR addr -> VMEM broadcast
    const float* bv  = make_divergent(b3T);

    float macc[48];
    #pragma unroll
    for (int l = 0; l < 48; ++l) macc[l] = 0.0f;

    const int obase = lane * 65;
    float ocur = s_o[obase];
    for (int ab = 0; ab < 64; ++ab) {
        const float onext = s_o[obase + ((ab + 1) & 63)];
        const float* brow = bv + ab * 48;
        float4 bcur;
        #pragma unroll
        for (int lo = 0; lo < 48; ++lo) {
            const float* wr = wab + lo * 64;
            float4 wv0 = *reinterpret_cast<const float4*>(wr);
            float4 wv1 = *reinterpret_cast<const float4*>(wr + 4);
            float4 wv2 = *reinterpret_cast<const float4*>(wr + 8);
            float4 wv3 = *reinterpret_cast<const float4*>(wr + 12);
            if ((lo & 3) == 0) bcur = *reinterpret_cast<const float4*>(brow + lo);
            float u0 = hc[0] * wv0.x;
            float u1 = hc[1] * wv0.y;
            u0 = fmaf(hc[2],  wv0.z, u0);
            u1 = fmaf(hc[3],  wv0.w, u1);
            u0 = fmaf(hc[4],  wv1.x, u0);
            u1 = fmaf(hc[5],  wv1.y, u1);
            u0 = fmaf(hc[6],  wv1.z, u0);
            u1 = fmaf(hc[7],  wv1.w, u1);
            u0 = fmaf(hc[8],  wv2.x, u0);
            u1 = fmaf(hc[9],  wv2.y, u1);
            u0 = fmaf(hc[10], wv2.z, u0);
            u1 = fmaf(hc[11], wv2.w, u1);
            u0 = fmaf(hc[12], wv3.x, u0);
            u1 = fmaf(hc[13], wv3.y, u1);
            u0 = fmaf(hc[14], wv3.z, u0);
            u1 = fmaf(hc[15], wv3.w, u1);
            const float bb = (lo & 3) == 0 ? bcur.x
                           : (lo & 3) == 1 ? bcur.y
                           : (lo & 3) == 2 ? bcur.z : bcur.w;
            const float t = fmaf(0.25f, bb, u0 + u1);
            macc[lo] = fmaf(t, ocur, macc[lo]);
        }
        wab += 3072;
        ocur = onext;
    }

    // ---- cross-wave reduction of macc -> ef, 3 groups of 16 lo ----
    const int mbase = p * 1088 + lane * 17;
    #pragma unroll
    for (int grp = 0; grp < 3; ++grp) {
        #pragma unroll
        for (int q = 0; q < 16; ++q) s_buf[mbase + q] = macc[grp * 16 + q];
        __syncthreads();
        {
            const int le = tid & 63;
            const int l0 = (tid >> 6) * 4;
            if (e0 + le < E) {
                float* dstp = ef + (size_t)(e0 + le) * 52 + grp * 16 + l0;
                const int idx = le * 17 + l0;
                float4 v;
                v.x = s_buf[idx + 0] + s_buf[1088 + idx + 0] + s_buf[2176 + idx + 0] + s_buf[3264 + idx + 0];
                v.y = s_buf[idx + 1] + s_buf[1088 + idx + 1] + s_buf[2176 + idx + 1] + s_buf[3264 + idx + 1];
                v.z = s_buf[idx + 2] + s_buf[1088 + idx + 2] + s_buf[2176 + idx + 2] + s_buf[3264 + idx + 2];
                v.w = s_buf[idx + 3] + s_buf[1088 + idx + 3] + s_buf[2176 + idx + 3] + s_buf[3264 + idx + 3];
                *reinterpret_cast<float4*>(dstp) = v;
            }
        }
        __syncthreads();
    }

    // ---- n + CSR scatter (one thread per edge) ----
    if (p == 0 && valid) {
        float* np = ef + (size_t)e * 52;
        np[48] = nx; np[49] = ny; np[50] = nz;
        int pp = atomicAdd(&cursor[dst], 1);
        eidx[pp] = e;
    }
}

// ---------------- kernel 6: gather-reduce per node ----------------
__global__ __launch_bounds__(256) void k_gather(const float* __restrict__ ef,
                                                const int* __restrict__ offs,
                                                const int* __restrict__ eidx,
                                                float* __restrict__ out, int N) {
    const int lane = threadIdx.x & 63;
    const int node = blockIdx.x * 4 + (threadIdx.x >> 6);
    if (node >= N) return;

    const int beg = offs[node];
    const int end = offs[node + 1];

    int mi[4], ii[4], jj[4], mode[4];
    #pragma unroll
    for (int t = 0; t < 4; ++t) {
        int c = lane + 64 * t;
        if (c < 16)       { mi[t] = c;                 ii[t] = 0;     jj[t] = 0;     mode[t] = 0; }
        else if (c < 64)  { int u = c - 16; mi[t] = 16 + u / 3; ii[t] = u % 3; jj[t] = 0; mode[t] = 1; }
        else if (c < 208) { int u = c - 64; mi[t] = 32 + u / 9; int rr = u % 9; ii[t] = rr / 3; jj[t] = rr % 3; mode[t] = 2; }
        else              { mi[t] = 0; ii[t] = 0; jj[t] = 0; mode[t] = 3; }
    }

    float acc[4] = {0.f, 0.f, 0.f, 0.f};
    for (int k = beg; k < end; ++k) {
        const int e = eidx[k];
        const float* b = ef + (size_t)e * 52;
        float v = (lane < 51) ? b[lane] : 0.0f;
        float n0 = __shfl(v, 48);
        float n1 = __shfl(v, 49);
        float n2 = __shfl(v, 50);
        #pragma unroll
        for (int t = 0; t < 4; ++t) {
            float mval = __shfl(v, mi[t]);
            float ni = (ii[t] == 0) ? n0 : ((ii[t] == 1) ? n1 : n2);
            float nj = (jj[t] == 0) ? n0 : ((jj[t] == 1) ? n1 : n2);
            float f  = (mode[t] == 0) ? 1.0f
                     : (mode[t] == 1) ? ni
                     : (mode[t] == 2) ? ni * nj
                     : 0.0f;
            acc[t] = fmaf(mval, f, acc[t]);
        }
    }

    const float inv = 1.0f / fmaxf((float)(end - beg), 1.0f);
    float* op = out + (size_t)node * 208;
    op[lane]        = acc[0] * inv;
    op[lane + 64]   = acc[1] * inv;
    op[lane + 128]  = acc[2] * inv;
    if (lane < 16) op[lane + 192] = acc[3] * inv;
}

extern "C" void kernel_launch(void* const* d_in, const int* in_sizes, int n_in,
                              void* d_out, int out_size, void* d_ws, size_t ws_size,
                              hipStream_t stream) {
    const float* pos    = (const float*)d_in[0];
    const int*   A      = (const int*)d_in[1];
    const int*   batch  = (const int*)d_in[2];
    const int*   esrc   = (const int*)d_in[3];
    const int*   edst   = (const int*)d_in[4];
    const float* eshift = (const float*)d_in[5];
    const float* cell   = (const float*)d_in[6];
    const float* embt   = (const float*)d_in[7];
    const float* mw1    = (const float*)d_in[8];
    const float* mb1    = (const float*)d_in[9];
    const float* mw2    = (const float*)d_in[10];
    const float* mb2    = (const float*)d_in[11];
    const float* fw1    = (const float*)d_in[12];
    const float* fb1    = (const float*)d_in[13];
    const float* fw2    = (const float*)d_in[14];
    const float* fb2    = (const float*)d_in[15];
    const float* w3     = (const float*)d_in[16];
    const float* b3     = (const float*)d_in[17];
    float* out = (float*)d_out;

    const int N = in_sizes[1];
    const int E = in_sizes[3];

    char* p = (char*)d_ws;
    auto take = [&](size_t bytes) {
        char* q = p;
        p += (bytes + 255) & ~(size_t)255;
        return q;
    };
    float* w3T2   = (float*)take(64 * 48 * 64 * sizeof(float));   // 768 KiB
    float* b3T    = (float*)take(64 * 48 * sizeof(float));        // 12 KiB
    float* Ai     = (float*)take((size_t)N * 8 * sizeof(float));
    int*   deg    = (int*)  take((size_t)N * sizeof(int));
    int*   offs   = (int*)  take((size_t)(N + 1) * sizeof(int));
    int*   cursor = (int*)  take((size_t)N * sizeof(int));
    int*   eidx   = (int*)  take((size_t)E * sizeof(int));
    float* ef     = (float*)take((size_t)E * 52 * sizeof(float)); // ~20.8 MiB

    hipMemsetAsync(deg, 0, (size_t)N * sizeof(int), stream);

    k_transpose_w3<<<(64 * 48 * 64 + 255) / 256, 256, 0, stream>>>(w3, b3, w3T2, b3T);
    k_node_ai<<<(N + 255) / 256, 256, 0, stream>>>(A, embt, mw1, mb1, mw2, mb2, Ai, N);
    k_hist<<<(E + 255) / 256, 256, 0, stream>>>(edst, deg, E);
    k_scan<<<1, 256, 0, stream>>>(deg, offs, cursor, N);
    k_edge<<<(E + 63) / 64, 256, 0, stream>>>(pos, batch, esrc, edst, eshift, cell,
                                              fw1, fb1, fw2, fb2, w3T2, b3T, Ai,
                                              ef, cursor, eidx, E);
    k_gather<<<(N + 3) / 4, 256, 0, stream>>>(ef, offs, eidx, out, N);
}

// Round 5
// 334.443 us; speedup vs baseline: 7.8669x; 7.8669x over previous
//
#include <hip/hip_runtime.h>
#include <math.h>
#include <stdint.h>

// Shapes (fixed by the reference)
// N=10000, E=100000, G=64, NB=16, EMB=16, S=8, COUT=16, LMAX=2
// WNUM = 3*16*8*8 = 3072 ; ef width = 16 + 48 + 144 = 208
// Per-edge compact result: m[48] (l*16+o) + n[3], stored as 52 floats.
//
// Main contraction as a fused GEMM via MFMA:
//   m[e][lo] = sum_{k=0}^{4159} z[e][k] * Bz[k][lo]
//   k < 4096 : k = ab*64 + c ;  z = o[e][ab]*h[e][c] ; Bz = w3[c][lo*64+ab]
//   k >= 4096: k = 4096 + ab  ;  z = o[e][ab]        ; Bz = b3[lo*64+ab]
// Both operands split into bf16 (hi + lo residual); 3 MFMA products
// (hi*hi + hi*lo + lo*hi), fp32 accumulation -> rel err ~2^-17 per term.

typedef float  f32x4  __attribute__((ext_vector_type(4)));
typedef short  s16x8  __attribute__((ext_vector_type(8)));
typedef __bf16 bf16x8 __attribute__((ext_vector_type(8)));

__device__ __forceinline__ float silu_f(float x) {
    return x / (1.0f + __expf(-x));
}

// ---------------- kernel 1: pack w3+b3 into MFMA B-fragment order, bf16 hi/lo ----------------
// K-step s (0..129): 32 k-values. s<128: ab=s>>1, c=(s&1)*32+klocal. s>=128: ab=(s-128)*32+klocal.
// Fragment lane l: col lo = t*16 + (l&15); klocal = (l>>4)*8 + j.
// Layout: wz[ ((s*3 + t)*2 + plane)*512 + l*8 + j ]  (ushort bf16)
__global__ __launch_bounds__(256) void k_prep(const float* __restrict__ w3,
                                              const float* __restrict__ b3,
                                              ushort* __restrict__ wz) {
    int t = blockIdx.x * 256 + threadIdx.x;
    if (t >= 130 * 3 * 512) return;
    int j    = t & 7;
    int l    = (t >> 3) & 63;
    int rest = t >> 9;          // s*3 + tt
    int tt   = rest % 3;
    int s    = rest / 3;
    int lo   = tt * 16 + (l & 15);
    int kl   = (l >> 4) * 8 + j;
    float v;
    if (s < 128) {
        int ab = s >> 1;
        int c  = (s & 1) * 32 + kl;
        v = w3[c * 3072 + lo * 64 + ab];
    } else {
        int ab = (s - 128) * 32 + kl;
        v = b3[lo * 64 + ab];
    }
    __bf16 hi  = (__bf16)v;
    __bf16 lor = (__bf16)(v - (float)hi);
    size_t base = (size_t)(s * 3 + tt) * 2 * 512 + l * 8 + j;
    wz[base]       = __builtin_bit_cast(ushort, hi);
    wz[base + 512] = __builtin_bit_cast(ushort, lor);
}

// ---------------- kernel 2: per-node Ai ----------------
__global__ __launch_bounds__(256) void k_node_ai(const int* __restrict__ A,
                                                 const float* __restrict__ embt,
                                                 const float* __restrict__ w1,
                                                 const float* __restrict__ b1,
                                                 const float* __restrict__ w2,
                                                 const float* __restrict__ b2,
                                                 float* __restrict__ Ai, int N) {
    int i = blockIdx.x * 256 + threadIdx.x;
    if (i >= N) return;
    float e[16];
    const float* er = embt + A[i] * 16;
    #pragma unroll
    for (int k = 0; k < 16; ++k) e[k] = er[k];
    float h1[64];
    #pragma unroll
    for (int j = 0; j < 64; ++j) {
        float a = b1[j];
        #pragma unroll
        for (int k = 0; k < 16; ++k) a = fmaf(e[k], w1[k * 64 + j], a);
        h1[j] = silu_f(a);
    }
    #pragma unroll
    for (int o = 0; o < 8; ++o) {
        float a = b2[o];
        #pragma unroll
        for (int j = 0; j < 64; ++j) a = fmaf(h1[j], w2[j * 8 + o], a);
        Ai[i * 8 + o] = a;
    }
}

// ---------------- kernel 3: histogram of edge_dst ----------------
__global__ __launch_bounds__(256) void k_hist(const int* __restrict__ edst,
                                              int* __restrict__ deg, int E) {
    int e = blockIdx.x * 256 + threadIdx.x;
    if (e < E) atomicAdd(&deg[edst[e]], 1);
}

// ---------------- kernel 4: single-block exclusive scan (N=10000) ----------------
__global__ __launch_bounds__(256) void k_scan(const int* __restrict__ deg,
                                              int* __restrict__ offs,
                                              int* __restrict__ cursor, int N) {
    __shared__ int part[256];
    const int t = threadIdx.x;
    const int chunk = (N + 255) / 256;
    const int beg = t * chunk;
    const int end = min(beg + chunk, N);
    int s = 0;
    for (int i = beg; i < end; ++i) s += deg[i];
    part[t] = s;
    __syncthreads();
    for (int off = 1; off < 256; off <<= 1) {
        int v = (t >= off) ? part[t - off] : 0;
        __syncthreads();
        part[t] += v;
        __syncthreads();
    }
    int run = (t == 0) ? 0 : part[t - 1];
    for (int i = beg; i < end; ++i) {
        offs[i] = run;
        cursor[i] = run;
        run += deg[i];
    }
    if (t == 255) offs[N] = part[255];
}

// ---------------- kernel 5: per-edge compute via MFMA ----------------
// Block = 256 threads = 4 waves = 64 edges. Front end (geometry/h1/h/o) is the
// verified round-3 c-split code. MFMA phase: wave w owns M-tile = edges
// [w*16, w*16+16); N = 48 lo (3 tiles of 16); K = 4160 in 65 chunks of 64
// (2 K-steps of 32). B (wz) reg-staged into an LDS double buffer per chunk.
__global__ __launch_bounds__(256) void k_edge(
    const float* __restrict__ pos, const int* __restrict__ batch,
    const int* __restrict__ esrc, const int* __restrict__ edst,
    const float* __restrict__ eshift, const float* __restrict__ cell,
    const float* __restrict__ fw1, const float* __restrict__ fb1,
    const float* __restrict__ fw2, const float* __restrict__ fb2,
    const ushort* __restrict__ wz,
    const float* __restrict__ Ai, float* __restrict__ ef,
    int* __restrict__ cursor, int* __restrict__ eidx, int E) {

    __shared__ float  s_h[64 * 68];     // phase1: h1 (stride 65); phase2: h (stride 68)
    __shared__ float  s_o[64 * 68];     // o[e][ab], stride 68 (16B-aligned rows, 2-way banks)
    __shared__ ushort sB[2][6144];      // B double buffer: 2 x 12 KB (one 64-K chunk)

    const int tid  = threadIdx.x;
    const int lane = tid & 63;                                   // edge slot (front end)
    const int w    = __builtin_amdgcn_readfirstlane(tid >> 6);   // wave id
    const int e0   = blockIdx.x * 64;
    const int e    = e0 + lane;
    const bool valid = (e < E);
    const int ec   = valid ? e : (E - 1);

    // ---- prologue: issue B chunk 0 loads early (hide under front end) ----
    const f32x4* wzv = reinterpret_cast<const f32x4*>(wz);
    f32x4 r0 = wzv[w * 192 + lane];
    f32x4 r1 = wzv[w * 192 + 64 + lane];
    f32x4 r2 = wzv[w * 192 + 128 + lane];

    const int src = esrc[ec];
    const int dst = edst[ec];

    // ---- geometry ----
    const int g0 = batch[src];
    const float s0 = eshift[ec * 3 + 0], s1 = eshift[ec * 3 + 1], s2 = eshift[ec * 3 + 2];
    const float* cl = cell + g0 * 9;
    float vx = pos[dst * 3 + 0] - pos[src * 3 + 0] + s0 * cl[0] + s1 * cl[3] + s2 * cl[6];
    float vy = pos[dst * 3 + 1] - pos[src * 3 + 1] + s0 * cl[1] + s1 * cl[4] + s2 * cl[7];
    float vz = pos[dst * 3 + 2] - pos[src * 3 + 2] + s0 * cl[2] + s1 * cl[5] + s2 * cl[8];
    float r = sqrtf(vx * vx + vy * vy + vz * vz);
    float rinv = 1.0f / fmaxf(r, 1e-9f);
    float nx = vx * rinv, ny = vy * rinv, nz = vz * rinv;

    // ---- radial basis (NB=16) ----
    float embv[16];
    const float step = 4.0f / 17.0f;
    const float sc = 4.0f / 1.12f;
    #pragma unroll
    for (int k = 0; k < 16; ++k) {
        float d = (r - (float)(k + 1) * step) / step;
        embv[k] = __expf(-d * d) * sc;
    }

    // ---- h1 chunk -> LDS (stride 65): wave w computes h1[j], j in [16w,16w+16) ----
    const int j0 = w * 16;
    #pragma unroll
    for (int jj = 0; jj < 16; ++jj) {
        const int j = j0 + jj;
        float a = fb1[j];
        #pragma unroll
        for (int k = 0; k < 16; ++k) a = fmaf(embv[k], fw1[k * 64 + j], a);
        s_h[lane * 65 + j] = silu_f(a);
    }

    // ---- o chunk -> LDS (stride 68): wave w computes o[ab], ab in [16w,16w+16) ----
    {
        const float* As = Ai + (size_t)src * 8;
        const float* Ad = Ai + (size_t)dst * 8;
        float fsa0 = As[2 * w], fsa1 = As[2 * w + 1];
        f32x4 d0 = *reinterpret_cast<const f32x4*>(Ad);
        f32x4 d1 = *reinterpret_cast<const f32x4*>(Ad + 4);
        float fdv[8] = {d0[0], d0[1], d0[2], d0[3], d1[0], d1[1], d1[2], d1[3]};
        const int ob = lane * 68 + j0;
        #pragma unroll
        for (int i = 0; i < 8; ++i)  s_o[ob + i]     = fsa0 * fdv[i];
        #pragma unroll
        for (int i = 0; i < 8; ++i)  s_o[ob + 8 + i] = fsa1 * fdv[i];
    }
    __syncthreads();   // h1 + o written

    // ---- hc chunk (registers): h[c], c in [16w,16w+16) ----
    float hc[16];
    #pragma unroll
    for (int i = 0; i < 16; ++i) hc[i] = fb2[j0 + i];
    #pragma unroll 4
    for (int j = 0; j < 64; ++j) {
        const float v = s_h[lane * 65 + j];
        const float* w2r = fw2 + j * 64 + j0;   // wave-uniform -> scalar
        #pragma unroll
        for (int i = 0; i < 16; ++i) hc[i] = fmaf(v, w2r[i], hc[i]);
    }
    #pragma unroll
    for (int i = 0; i < 16; ++i) hc[i] = silu_f(hc[i]);
    __syncthreads();   // all h1 reads done -> s_h becomes h (stride 68)

    #pragma unroll
    for (int i = 0; i < 16; ++i) s_h[lane * 68 + j0 + i] = hc[i];
    // (first K-loop barrier makes these visible to all waves)

    // ---- MFMA phase ----
    const int g  = lane >> 4;                       // k-group 0..3
    const int er = w * 16 + (lane & 15);            // A-row edge (block-local)
    const float* hrow = s_h + er * 68;
    const float* orow = s_o + er * 68;

    f32x4 acc0 = {0.f, 0.f, 0.f, 0.f};
    f32x4 acc1 = {0.f, 0.f, 0.f, 0.f};
    f32x4 acc2 = {0.f, 0.f, 0.f, 0.f};

    auto run_step = [&](f32x4 v0, f32x4 v1, float scale, const ushort* bbuf, int sl) {
        float zz[8];
        #pragma unroll
        for (int k2 = 0; k2 < 4; ++k2) { zz[k2] = scale * v0[k2]; zz[k2 + 4] = scale * v1[k2]; }
        bf16x8 ah, al;
        #pragma unroll
        for (int k2 = 0; k2 < 8; ++k2) {
            __bf16 hi = (__bf16)zz[k2];
            ah[k2] = hi;
            al[k2] = (__bf16)(zz[k2] - (float)hi);
        }
        s16x8 Ah = __builtin_bit_cast(s16x8, ah);
        s16x8 Al = __builtin_bit_cast(s16x8, al);
        #pragma unroll
        for (int t = 0; t < 3; ++t) {
            const int fo = ((sl * 3 + t) * 2) * 512 + lane * 8;
            s16x8 Bh = *reinterpret_cast<const s16x8*>(&bbuf[fo]);
            s16x8 Bl = *reinterpret_cast<const s16x8*>(&bbuf[fo + 512]);
            f32x4& ac = (t == 0) ? acc0 : (t == 1) ? acc1 : acc2;
            ac = __builtin_amdgcn_mfma_f32_16x16x32_bf16(Ah, Bh, ac, 0, 0, 0);
            ac = __builtin_amdgcn_mfma_f32_16x16x32_bf16(Ah, Bl, ac, 0, 0, 0);
            ac = __builtin_amdgcn_mfma_f32_16x16x32_bf16(Al, Bh, ac, 0, 0, 0);
        }
    };

    for (int u = 0; u < 65; ++u) {
        const int bs = u & 1;
        // commit staged regs to LDS (each wave owns 3 KB of the 12 KB chunk)
        f32x4* db = reinterpret_cast<f32x4*>(&sB[bs][w * 1536]);
        db[lane]       = r0;
        db[64 + lane]  = r1;
        db[128 + lane] = r2;
        __syncthreads();
        if (u < 64) {   // issue next chunk's loads; latency hides under compute
            const f32x4* gs = wzv + (size_t)(u + 1) * 768 + w * 192;
            r0 = gs[lane];
            r1 = gs[64 + lane];
            r2 = gs[128 + lane];
        }
        const ushort* bbuf = sB[bs];
        if (u < 64) {
            const float oe = orow[u];   // ab = u
            f32x4 ha = *reinterpret_cast<const f32x4*>(&hrow[g * 8]);
            f32x4 hb = *reinterpret_cast<const f32x4*>(&hrow[g * 8 + 4]);
            run_step(ha, hb, oe, bbuf, 0);
            f32x4 hc0 = *reinterpret_cast<const f32x4*>(&hrow[32 + g * 8]);
            f32x4 hd = *reinterpret_cast<const f32x4*>(&hrow[32 + g * 8 + 4]);
            run_step(hc0, hd, oe, bbuf, 1);
        } else {
            // bias rows: z = o[ab]
            f32x4 oa = *reinterpret_cast<const f32x4*>(&orow[g * 8]);
            f32x4 ob = *reinterpret_cast<const f32x4*>(&orow[g * 8 + 4]);
            run_step(oa, ob, 1.0f, bbuf, 0);
            f32x4 oc = *reinterpret_cast<const f32x4*>(&orow[32 + g * 8]);
            f32x4 od = *reinterpret_cast<const f32x4*>(&orow[32 + g * 8 + 4]);
            run_step(oc, od, 1.0f, bbuf, 1);
        }
    }

    // ---- write m: D row = (lane>>4)*4 + i (edge), col = lane&15 (lo) ----
    #pragma unroll
    for (int t = 0; t < 3; ++t) {
        const f32x4 ac = (t == 0) ? acc0 : (t == 1) ? acc1 : acc2;
        #pragma unroll
        for (int i = 0; i < 4; ++i) {
            const int ee = e0 + w * 16 + g * 4 + i;
            if (ee < E) ef[(size_t)ee * 52 + t * 16 + (lane & 15)] = ac[i];
        }
    }

    // ---- n + CSR scatter (one thread per edge) ----
    if (w == 0 && valid) {
        float* np = ef + (size_t)e * 52;
        np[48] = nx; np[49] = ny; np[50] = nz;
        int pp = atomicAdd(&cursor[dst], 1);
        eidx[pp] = e;
    }
}

// ---------------- kernel 6: gather-reduce per node ----------------
__global__ __launch_bounds__(256) void k_gather(const float* __restrict__ ef,
                                                const int* __restrict__ offs,
                                                const int* __restrict__ eidx,
                                                float* __restrict__ out, int N) {
    const int lane = threadIdx.x & 63;
    const int node = blockIdx.x * 4 + (threadIdx.x >> 6);
    if (node >= N) return;

    const int beg = offs[node];
    const int end = offs[node + 1];

    int mi[4], ii[4], jj[4], mode[4];
    #pragma unroll
    for (int t = 0; t < 4; ++t) {
        int c = lane + 64 * t;
        if (c < 16)       { mi[t] = c;                 ii[t] = 0;     jj[t] = 0;     mode[t] = 0; }
        else if (c < 64)  { int u = c - 16; mi[t] = 16 + u / 3; ii[t] = u % 3; jj[t] = 0; mode[t] = 1; }
        else if (c < 208) { int u = c - 64; mi[t] = 32 + u / 9; int rr = u % 9; ii[t] = rr / 3; jj[t] = rr % 3; mode[t] = 2; }
        else              { mi[t] = 0; ii[t] = 0; jj[t] = 0; mode[t] = 3; }
    }

    float acc[4] = {0.f, 0.f, 0.f, 0.f};
    for (int k = beg; k < end; ++k) {
        const int e = eidx[k];
        const float* b = ef + (size_t)e * 52;
        float v = (lane < 51) ? b[lane] : 0.0f;
        float n0 = __shfl(v, 48);
        float n1 = __shfl(v, 49);
        float n2 = __shfl(v, 50);
        #pragma unroll
        for (int t = 0; t < 4; ++t) {
            float mval = __shfl(v, mi[t]);
            float ni = (ii[t] == 0) ? n0 : ((ii[t] == 1) ? n1 : n2);
            float nj = (jj[t] == 0) ? n0 : ((jj[t] == 1) ? n1 : n2);
            float f  = (mode[t] == 0) ? 1.0f
                     : (mode[t] == 1) ? ni
                     : (mode[t] == 2) ? ni * nj
                     : 0.0f;
            acc[t] = fmaf(mval, f, acc[t]);
        }
    }

    const float inv = 1.0f / fmaxf((float)(end - beg), 1.0f);
    float* op = out + (size_t)node * 208;
    op[lane]        = acc[0] * inv;
    op[lane + 64]   = acc[1] * inv;
    op[lane + 128]  = acc[2] * inv;
    if (lane < 16) op[lane + 192] = acc[3] * inv;
}

extern "C" void kernel_launch(void* const* d_in, const int* in_sizes, int n_in,
                              void* d_out, int out_size, void* d_ws, size_t ws_size,
                              hipStream_t stream) {
    const float* pos    = (const float*)d_in[0];
    const int*   A      = (const int*)d_in[1];
    const int*   batch  = (const int*)d_in[2];
    const int*   esrc   = (const int*)d_in[3];
    const int*   edst   = (const int*)d_in[4];
    const float* eshift = (const float*)d_in[5];
    const float* cell   = (const float*)d_in[6];
    const float* embt   = (const float*)d_in[7];
    const float* mw1    = (const float*)d_in[8];
    const float* mb1    = (const float*)d_in[9];
    const float* mw2    = (const float*)d_in[10];
    const float* mb2    = (const float*)d_in[11];
    const float* fw1    = (const float*)d_in[12];
    const float* fb1    = (const float*)d_in[13];
    const float* fw2    = (const float*)d_in[14];
    const float* fb2    = (const float*)d_in[15];
    const float* w3     = (const float*)d_in[16];
    const float* b3     = (const float*)d_in[17];
    float* out = (float*)d_out;

    const int N = in_sizes[1];
    const int E = in_sizes[3];

    char* p = (char*)d_ws;
    auto take = [&](size_t bytes) {
        char* q = p;
        p += (bytes + 255) & ~(size_t)255;
        return q;
    };
    ushort* wz    = (ushort*)take((size_t)130 * 3 * 2 * 512 * sizeof(ushort)); // 798,720 B
    float* Ai     = (float*)take((size_t)N * 8 * sizeof(float));
    int*   deg    = (int*)  take((size_t)N * sizeof(int));
    int*   offs   = (int*)  take((size_t)(N + 1) * sizeof(int));
    int*   cursor = (int*)  take((size_t)N * sizeof(int));
    int*   eidx   = (int*)  take((size_t)E * sizeof(int));
    float* ef     = (float*)take((size_t)E * 52 * sizeof(float)); // ~20.8 MiB

    hipMemsetAsync(deg, 0, (size_t)N * sizeof(int), stream);

    k_prep<<<(130 * 3 * 512 + 255) / 256, 256, 0, stream>>>(w3, b3, wz);
    k_node_ai<<<(N + 255) / 256, 256, 0, stream>>>(A, embt, mw1, mb1, mw2, mb2, Ai, N);
    k_hist<<<(E + 255) / 256, 256, 0, stream>>>(edst, deg, E);
    k_scan<<<1, 256, 0, stream>>>(deg, offs, cursor, N);
    k_edge<<<(E + 63) / 64, 256, 0, stream>>>(pos, batch, esrc, edst, eshift, cell,
                                              fw1, fb1, fw2, fb2, wz, Ai,
                                              ef, cursor, eidx, E);
    k_gather<<<(N + 3) / 4, 256, 0, stream>>>(ef, offs, eidx, out, N);
}

// Round 6
// 248.187 us; speedup vs baseline: 10.6010x; 1.3475x over previous
//
#include <hip/hip_runtime.h>
#include <math.h>
#include <stdint.h>

// Shapes (fixed by the reference)
// N=10000, E=100000, G=64, NB=16, EMB=16, S=8, COUT=16, LMAX=2
// WNUM = 3*16*8*8 = 3072 ; ef width = 16 + 48 + 144 = 208
// Per-edge compact result: m[48] (l*16+o) + n[3], stored as 52 floats.
//
// Main contraction as a fused GEMM via MFMA:
//   m[e][lo] = sum_ab o[e][ab] * ( sum_c h[e][c] * w3[c][lo*64+ab] ) + bias
// Per K-chunk u (= one ab), MFMA computes D = (h . B_ab) with h split into
// bf16 hi+lo (3 products, fp32 accum); then acc += o[e][ab] * D with o in
// EXACT fp32 (no per-step operand rebuild). Bias rows use once-split o frags.

typedef float  f32x4  __attribute__((ext_vector_type(4)));
typedef short  s16x8  __attribute__((ext_vector_type(8)));
typedef __bf16 bf16x8 __attribute__((ext_vector_type(8)));

__device__ __forceinline__ float silu_f(float x) {
    return x / (1.0f + __expf(-x));
}

// split 8 f32 (two f32x4, k-local order j=0..7) into bf16 hi + lo fragments
__device__ __forceinline__ void split8(f32x4 a, f32x4 b, s16x8& hi, s16x8& lo) {
    bf16x8 h8, l8;
    #pragma unroll
    for (int i = 0; i < 4; ++i) {
        float z = a[i]; __bf16 zh = (__bf16)z; h8[i] = zh; l8[i] = (__bf16)(z - (float)zh);
        float y = b[i]; __bf16 yh = (__bf16)y; h8[4 + i] = yh; l8[4 + i] = (__bf16)(y - (float)yh);
    }
    hi = __builtin_bit_cast(s16x8, h8);
    lo = __builtin_bit_cast(s16x8, l8);
}

// ---------------- kernel 1 (fused setup): prep wz | node Ai | edge_dst hist ----------------
// K-step s (0..129): 32 k-values. s<128: ab=s>>1, c=(s&1)*32+kl. s>=128: ab=(s-128)*32+kl.
// Fragment lane l: col lo = t*16 + (l&15); kl = (l>>4)*8 + j.
// wz[ ((s*3 + t)*2 + plane)*512 + l*8 + j ]  (ushort bf16)
__global__ __launch_bounds__(256) void k_setup(const float* __restrict__ w3,
                                               const float* __restrict__ b3,
                                               ushort* __restrict__ wz,
                                               const int* __restrict__ A,
                                               const float* __restrict__ embt,
                                               const float* __restrict__ w1,
                                               const float* __restrict__ b1,
                                               const float* __restrict__ w2,
                                               const float* __restrict__ b2,
                                               float* __restrict__ Ai,
                                               const int* __restrict__ edst,
                                               int* __restrict__ deg,
                                               int N, int E, int aiB) {
    const int b = blockIdx.x;
    const int tid = threadIdx.x;
    if (b < 780) {                         // ---- prep: 780*256 = 199680 = 130*3*512
        int t = b * 256 + tid;
        int j    = t & 7;
        int l    = (t >> 3) & 63;
        int rest = t >> 9;          // s*3 + tt
        int tt   = rest % 3;
        int s    = rest / 3;
        int lo   = tt * 16 + (l & 15);
        int kl   = (l >> 4) * 8 + j;
        float v;
        if (s < 128) {
            int ab = s >> 1;
            int c  = (s & 1) * 32 + kl;
            v = w3[c * 3072 + lo * 64 + ab];
        } else {
            int ab = (s - 128) * 32 + kl;
            v = b3[lo * 64 + ab];
        }
        __bf16 hi  = (__bf16)v;
        __bf16 lor = (__bf16)(v - (float)hi);
        size_t base = (size_t)(s * 3 + tt) * 2 * 512 + l * 8 + j;
        wz[base]       = __builtin_bit_cast(ushort, hi);
        wz[base + 512] = __builtin_bit_cast(ushort, lor);
    } else if (b < 780 + aiB) {            // ---- node Ai
        int i = (b - 780) * 256 + tid;
        if (i >= N) return;
        float e[16];
        const float* er = embt + A[i] * 16;
        #pragma unroll
        for (int k = 0; k < 16; ++k) e[k] = er[k];
        float h1[64];
        #pragma unroll
        for (int j = 0; j < 64; ++j) {
            float a = b1[j];
            #pragma unroll
            for (int k = 0; k < 16; ++k) a = fmaf(e[k], w1[k * 64 + j], a);
            h1[j] = silu_f(a);
        }
        #pragma unroll
        for (int o = 0; o < 8; ++o) {
            float a = b2[o];
            #pragma unroll
            for (int j = 0; j < 64; ++j) a = fmaf(h1[j], w2[j * 8 + o], a);
            Ai[i * 8 + o] = a;
        }
    } else {                               // ---- histogram of edge_dst
        int e = (b - 780 - aiB) * 256 + tid;
        if (e < E) atomicAdd(&deg[edst[e]], 1);
    }
}

// ---------------- kernel 2: single-block exclusive scan (N=10000), 1024 threads ----------------
__global__ __launch_bounds__(1024) void k_scan(const int* __restrict__ deg,
                                               int* __restrict__ offs,
                                               int* __restrict__ cursor, int N) {
    __shared__ int part[1024];
    const int t = threadIdx.x;
    const int chunk = (N + 1023) / 1024;
    const int beg = t * chunk;
    const int end = min(beg + chunk, N);
    int s = 0;
    for (int i = beg; i < end; ++i) s += deg[i];
    part[t] = s;
    __syncthreads();
    for (int off = 1; off < 1024; off <<= 1) {
        int v = (t >= off) ? part[t - off] : 0;
        __syncthreads();
        part[t] += v;
        __syncthreads();
    }
    int run = (t == 0) ? 0 : part[t - 1];
    for (int i = beg; i < end; ++i) {
        offs[i] = run;
        cursor[i] = run;
        run += deg[i];
    }
    if (t == 1023) offs[N] = part[1023];
}

// ---------------- kernel 3: per-edge compute via MFMA ----------------
// Block = 256 threads = 4 waves = 128 edges (M=32 per wave: 2 x 16-row tiles).
// Front end (verified round-5 code) runs twice (rows 0-63, 64-127); h moves to
// per-lane bf16 hi/lo fragments (registers), freeing its LDS for the B buffer.
// K-loop per u: 12 B-frag ds_read_b128 + 36 MFMA + o-scale fp32 FMAs.
__global__ __launch_bounds__(256, 2) void k_edge(
    const float* __restrict__ pos, const int* __restrict__ batch,
    const int* __restrict__ esrc, const int* __restrict__ edst,
    const float* __restrict__ eshift, const float* __restrict__ cell,
    const float* __restrict__ fw1, const float* __restrict__ fb1,
    const float* __restrict__ fw2, const float* __restrict__ fb2,
    const ushort* __restrict__ wz,
    const float* __restrict__ Ai, float* __restrict__ ef,
    int* __restrict__ cursor, int* __restrict__ eidx, int E) {

    // s_un: phase A = h1 (stride 65) then h (stride 68); phase B = B double buffer.
    __shared__ __align__(16) float s_un[8704];   // 34816 B
    __shared__ __align__(16) float s_o[8704];    // o[128 edges][68-stride]

    const int tid  = threadIdx.x;
    const int lane = tid & 63;
    const int w    = __builtin_amdgcn_readfirstlane(tid >> 6);   // wave id
    const int e0   = blockIdx.x * 128;
    const int j0   = w * 16;                                     // c-chunk

    // ---- prologue: issue B chunk 0 loads early ----
    const f32x4* wzv = reinterpret_cast<const f32x4*>(wz);
    f32x4 r0 = wzv[w * 192 + lane];
    f32x4 r1 = wzv[w * 192 + 64 + lane];
    f32x4 r2 = wzv[w * 192 + 128 + lane];

    // ---- front end, two rounds of 64 edges ----
    #pragma unroll
    for (int rr = 0; rr < 2; ++rr) {
        const int e = e0 + rr * 64 + lane;
        const bool valid = (e < E);
        const int ec = valid ? e : (E - 1);
        const int src = esrc[ec];
        const int dst = edst[ec];

        const int g0 = batch[src];
        const float s0 = eshift[ec * 3 + 0], s1 = eshift[ec * 3 + 1], s2 = eshift[ec * 3 + 2];
        const float* cl = cell + g0 * 9;
        float vx = pos[dst * 3 + 0] - pos[src * 3 + 0] + s0 * cl[0] + s1 * cl[3] + s2 * cl[6];
        float vy = pos[dst * 3 + 1] - pos[src * 3 + 1] + s0 * cl[1] + s1 * cl[4] + s2 * cl[7];
        float vz = pos[dst * 3 + 2] - pos[src * 3 + 2] + s0 * cl[2] + s1 * cl[5] + s2 * cl[8];
        float r = sqrtf(vx * vx + vy * vy + vz * vz);
        float rinv = 1.0f / fmaxf(r, 1e-9f);
        float nx = vx * rinv, ny = vy * rinv, nz = vz * rinv;

        float embv[16];
        const float step = 4.0f / 17.0f;
        const float sc = 4.0f / 1.12f;
        #pragma unroll
        for (int k = 0; k < 16; ++k) {
            float d = (r - (float)(k + 1) * step) / step;
            embv[k] = __expf(-d * d) * sc;
        }

        // h1 chunk -> s_un (stride 65)
        const int hb = (rr * 64 + lane) * 65;
        #pragma unroll
        for (int jj = 0; jj < 16; ++jj) {
            const int j = j0 + jj;
            float a = fb1[j];
            #pragma unroll
            for (int k = 0; k < 16; ++k) a = fmaf(embv[k], fw1[k * 64 + j], a);
            s_un[hb + j] = silu_f(a);
        }

        // o chunk -> s_o (stride 68)
        {
            const float* As = Ai + (size_t)src * 8;
            const float* Ad = Ai + (size_t)dst * 8;
            float fsa0 = As[2 * w], fsa1 = As[2 * w + 1];
            f32x4 d0 = *reinterpret_cast<const f32x4*>(Ad);
            f32x4 d1 = *reinterpret_cast<const f32x4*>(Ad + 4);
            float fdv[8] = {d0[0], d0[1], d0[2], d0[3], d1[0], d1[1], d1[2], d1[3]};
            const int ob = (rr * 64 + lane) * 68 + j0;
            #pragma unroll
            for (int i = 0; i < 8; ++i)  s_o[ob + i]     = fsa0 * fdv[i];
            #pragma unroll
            for (int i = 0; i < 8; ++i)  s_o[ob + 8 + i] = fsa1 * fdv[i];
        }

        // n + CSR scatter (one thread per edge)
        if (w == 0 && valid) {
            float* np = ef + (size_t)e * 52;
            np[48] = nx; np[49] = ny; np[50] = nz;
            int pp = atomicAdd(&cursor[dst], 1);
            eidx[pp] = e;
        }
    }
    __syncthreads();

    // ---- hc chunks (registers) for both rounds ----
    float hcr[2][16];
    #pragma unroll
    for (int rr = 0; rr < 2; ++rr) {
        const int hb = (rr * 64 + lane) * 65;
        #pragma unroll
        for (int i = 0; i < 16; ++i) hcr[rr][i] = fb2[j0 + i];
        #pragma unroll 4
        for (int j = 0; j < 64; ++j) {
            const float v = s_un[hb + j];
            const float* w2r = fw2 + j * 64 + j0;   // wave-uniform -> scalar
            #pragma unroll
            for (int i = 0; i < 16; ++i) hcr[rr][i] = fmaf(v, w2r[i], hcr[rr][i]);
        }
        #pragma unroll
        for (int i = 0; i < 16; ++i) hcr[rr][i] = silu_f(hcr[rr][i]);
    }
    __syncthreads();   // all h1 reads done -> rewrite region at stride 68

    #pragma unroll
    for (int rr = 0; rr < 2; ++rr) {
        const int hb = (rr * 64 + lane) * 68 + j0;
        #pragma unroll
        for (int i = 0; i < 16; ++i) s_un[hb + i] = hcr[rr][i];
    }
    __syncthreads();

    // ---- extract per-lane A (h) and O (bias) fragments, then free s_un ----
    const int g = lane >> 4;                 // k-group
    const int mrow = w * 32 + (lane & 15);   // M-tile 0 row
    s16x8 AhF[2][2], AlF[2][2], OhF[2][2], OlF[2][2];
    #pragma unroll
    for (int mt = 0; mt < 2; ++mt) {
        const float* hr = s_un + (mrow + mt * 16) * 68;
        const float* orw = s_o + (mrow + mt * 16) * 68;
        f32x4 a0 = *reinterpret_cast<const f32x4*>(hr + g * 8);
        f32x4 a1 = *reinterpret_cast<const f32x4*>(hr + g * 8 + 4);
        split8(a0, a1, AhF[mt][0], AlF[mt][0]);
        f32x4 a2 = *reinterpret_cast<const f32x4*>(hr + 32 + g * 8);
        f32x4 a3 = *reinterpret_cast<const f32x4*>(hr + 32 + g * 8 + 4);
        split8(a2, a3, AhF[mt][1], AlF[mt][1]);
        f32x4 o0 = *reinterpret_cast<const f32x4*>(orw + g * 8);
        f32x4 o1 = *reinterpret_cast<const f32x4*>(orw + g * 8 + 4);
        split8(o0, o1, OhF[mt][0], OlF[mt][0]);
        f32x4 o2 = *reinterpret_cast<const f32x4*>(orw + 32 + g * 8);
        f32x4 o3 = *reinterpret_cast<const f32x4*>(orw + 32 + g * 8 + 4);
        split8(o2, o3, OhF[mt][1], OlF[mt][1]);
    }
    __syncthreads();   // s_un now free -> becomes B double buffer

    ushort* sBb = reinterpret_cast<ushort*>(s_un);
    const int rb = w * 32 + (lane >> 4) * 4;   // first output row of this lane's D

    f32x4 acc[2][3];
    #pragma unroll
    for (int mt = 0; mt < 2; ++mt)
        #pragma unroll
        for (int t = 0; t < 3; ++t) acc[mt][t] = (f32x4){0.f, 0.f, 0.f, 0.f};

    for (int u = 0; u < 65; ++u) {
        const int bs = u & 1;
        f32x4* db = reinterpret_cast<f32x4*>(sBb + bs * 6144 + w * 1536);
        db[lane]       = r0;
        db[64 + lane]  = r1;
        db[128 + lane] = r2;
        __syncthreads();
        if (u < 64) {   // issue next chunk's loads; latency hides under compute
            const f32x4* gs = wzv + (size_t)(u + 1) * 768 + w * 192;
            r0 = gs[lane];
            r1 = gs[64 + lane];
            r2 = gs[128 + lane];
        }
        const ushort* bbuf = sBb + bs * 6144;
        if (u < 64) {
            // o for the 8 output rows this lane covers (broadcast within 16-lane groups)
            float ov[8];
            #pragma unroll
            for (int i = 0; i < 4; ++i) {
                ov[i]     = s_o[(rb + i) * 68 + u];
                ov[4 + i] = s_o[(rb + 16 + i) * 68 + u];
            }
            #pragma unroll
            for (int t = 0; t < 3; ++t) {
                f32x4 D0 = {0.f, 0.f, 0.f, 0.f};
                f32x4 D1 = {0.f, 0.f, 0.f, 0.f};
                #pragma unroll
                for (int sl = 0; sl < 2; ++sl) {
                    const int fo = ((sl * 3 + t) * 2) * 512 + lane * 8;
                    s16x8 Bh = *reinterpret_cast<const s16x8*>(bbuf + fo);
                    s16x8 Bl = *reinterpret_cast<const s16x8*>(bbuf + fo + 512);
                    D0 = __builtin_amdgcn_mfma_f32_16x16x32_bf16(AhF[0][sl], Bh, D0, 0, 0, 0);
                    D0 = __builtin_amdgcn_mfma_f32_16x16x32_bf16(AhF[0][sl], Bl, D0, 0, 0, 0);
                    D0 = __builtin_amdgcn_mfma_f32_16x16x32_bf16(AlF[0][sl], Bh, D0, 0, 0, 0);
                    D1 = __builtin_amdgcn_mfma_f32_16x16x32_bf16(AhF[1][sl], Bh, D1, 0, 0, 0);
                    D1 = __builtin_amdgcn_mfma_f32_16x16x32_bf16(AhF[1][sl], Bl, D1, 0, 0, 0);
                    D1 = __builtin_amdgcn_mfma_f32_16x16x32_bf16(AlF[1][sl], Bh, D1, 0, 0, 0);
                }
                #pragma unroll
                for (int i = 0; i < 4; ++i) {
                    acc[0][t][i] = fmaf(ov[i],     D0[i], acc[0][t][i]);
                    acc[1][t][i] = fmaf(ov[4 + i], D1[i], acc[1][t][i]);
                }
            }
        } else {
            // bias rows: z = o (once-split fragments), direct accumulation
            #pragma unroll
            for (int t = 0; t < 3; ++t) {
                #pragma unroll
                for (int sl = 0; sl < 2; ++sl) {
                    const int fo = ((sl * 3 + t) * 2) * 512 + lane * 8;
                    s16x8 Bh = *reinterpret_cast<const s16x8*>(bbuf + fo);
                    s16x8 Bl = *reinterpret_cast<const s16x8*>(bbuf + fo + 512);
                    acc[0][t] = __builtin_amdgcn_mfma_f32_16x16x32_bf16(OhF[0][sl], Bh, acc[0][t], 0, 0, 0);
                    acc[0][t] = __builtin_amdgcn_mfma_f32_16x16x32_bf16(OhF[0][sl], Bl, acc[0][t], 0, 0, 0);
                    acc[0][t] = __builtin_amdgcn_mfma_f32_16x16x32_bf16(OlF[0][sl], Bh, acc[0][t], 0, 0, 0);
                    acc[1][t] = __builtin_amdgcn_mfma_f32_16x16x32_bf16(OhF[1][sl], Bh, acc[1][t], 0, 0, 0);
                    acc[1][t] = __builtin_amdgcn_mfma_f32_16x16x32_bf16(OhF[1][sl], Bl, acc[1][t], 0, 0, 0);
                    acc[1][t] = __builtin_amdgcn_mfma_f32_16x16x32_bf16(OlF[1][sl], Bh, acc[1][t], 0, 0, 0);
                }
            }
        }
    }

    // ---- write m: D row = rb + i (edge), col = lane&15 (lo) ----
    #pragma unroll
    for (int mt = 0; mt < 2; ++mt) {
        #pragma unroll
        for (int t = 0; t < 3; ++t) {
            #pragma unroll
            for (int i = 0; i < 4; ++i) {
                const int ee = e0 + rb + mt * 16 + i;
                if (ee < E) ef[(size_t)ee * 52 + t * 16 + (lane & 15)] = acc[mt][t][i];
            }
        }
    }
}

// ---------------- kernel 4: gather-reduce per node ----------------
__global__ __launch_bounds__(256) void k_gather(const float* __restrict__ ef,
                                                const int* __restrict__ offs,
                                                const int* __restrict__ eidx,
                                                float* __restrict__ out, int N) {
    const int lane = threadIdx.x & 63;
    const int node = blockIdx.x * 4 + (threadIdx.x >> 6);
    if (node >= N) return;

    const int beg = offs[node];
    const int end = offs[node + 1];

    int mi[4], ii[4], jj[4], mode[4];
    #pragma unroll
    for (int t = 0; t < 4; ++t) {
        int c = lane + 64 * t;
        if (c < 16)       { mi[t] = c;                 ii[t] = 0;     jj[t] = 0;     mode[t] = 0; }
        else if (c < 64)  { int u = c - 16; mi[t] = 16 + u / 3; ii[t] = u % 3; jj[t] = 0; mode[t] = 1; }
        else if (c < 208) { int u = c - 64; mi[t] = 32 + u / 9; int rr = u % 9; ii[t] = rr / 3; jj[t] = rr % 3; mode[t] = 2; }
        else              { mi[t] = 0; ii[t] = 0; jj[t] = 0; mode[t] = 3; }
    }

    float acc[4] = {0.f, 0.f, 0.f, 0.f};
    for (int k = beg; k < end; ++k) {
        const int e = eidx[k];
        const float* b = ef + (size_t)e * 52;
        float v = (lane < 51) ? b[lane] : 0.0f;
        float n0 = __shfl(v, 48);
        float n1 = __shfl(v, 49);
        float n2 = __shfl(v, 50);
        #pragma unroll
        for (int t = 0; t < 4; ++t) {
            float mval = __shfl(v, mi[t]);
            float ni = (ii[t] == 0) ? n0 : ((ii[t] == 1) ? n1 : n2);
            float nj = (jj[t] == 0) ? n0 : ((jj[t] == 1) ? n1 : n2);
            float f  = (mode[t] == 0) ? 1.0f
                     : (mode[t] == 1) ? ni
                     : (mode[t] == 2) ? ni * nj
                     : 0.0f;
            acc[t] = fmaf(mval, f, acc[t]);
        }
    }

    const float inv = 1.0f / fmaxf((float)(end - beg), 1.0f);
    float* op = out + (size_t)node * 208;
    op[lane]        = acc[0] * inv;
    op[lane + 64]   = acc[1] * inv;
    op[lane + 128]  = acc[2] * inv;
    if (lane < 16) op[lane + 192] = acc[3] * inv;
}

extern "C" void kernel_launch(void* const* d_in, const int* in_sizes, int n_in,
                              void* d_out, int out_size, void* d_ws, size_t ws_size,
                              hipStream_t stream) {
    const float* pos    = (const float*)d_in[0];
    const int*   A      = (const int*)d_in[1];
    const int*   batch  = (const int*)d_in[2];
    const int*   esrc   = (const int*)d_in[3];
    const int*   edst   = (const int*)d_in[4];
    const float* eshift = (const float*)d_in[5];
    const float* cell   = (const float*)d_in[6];
    const float* embt   = (const float*)d_in[7];
    const float* mw1    = (const float*)d_in[8];
    const float* mb1    = (const float*)d_in[9];
    const float* mw2    = (const float*)d_in[10];
    const float* mb2    = (const float*)d_in[11];
    const float* fw1    = (const float*)d_in[12];
    const float* fb1    = (const float*)d_in[13];
    const float* fw2    = (const float*)d_in[14];
    const float* fb2    = (const float*)d_in[15];
    const float* w3     = (const float*)d_in[16];
    const float* b3     = (const float*)d_in[17];
    float* out = (float*)d_out;

    const int N = in_sizes[1];
    const int E = in_sizes[3];

    char* p = (char*)d_ws;
    auto take = [&](size_t bytes) {
        char* q = p;
        p += (bytes + 255) & ~(size_t)255;
        return q;
    };
    ushort* wz    = (ushort*)take((size_t)130 * 3 * 2 * 512 * sizeof(ushort)); // ~780 KiB
    float* Ai     = (float*)take((size_t)N * 8 * sizeof(float));
    int*   deg    = (int*)  take((size_t)N * sizeof(int));
    int*   offs   = (int*)  take((size_t)(N + 1) * sizeof(int));
    int*   cursor = (int*)  take((size_t)N * sizeof(int));
    int*   eidx   = (int*)  take((size_t)E * sizeof(int));
    float* ef     = (float*)take((size_t)E * 52 * sizeof(float)); // ~20.8 MiB

    hipMemsetAsync(deg, 0, (size_t)N * sizeof(int), stream);

    const int aiB = (N + 255) / 256;
    const int histB = (E + 255) / 256;
    k_setup<<<780 + aiB + histB, 256, 0, stream>>>(w3, b3, wz, A, embt, mw1, mb1,
                                                   mw2, mb2, Ai, edst, deg, N, E, aiB);
    k_scan<<<1, 1024, 0, stream>>>(deg, offs, cursor, N);
    k_edge<<<(E + 127) / 128, 256, 0, stream>>>(pos, batch, esrc, edst, eshift, cell,
                                                fw1, fb1, fw2, fb2, wz, Ai,
                                                ef, cursor, eidx, E);
    k_gather<<<(N + 3) / 4, 256, 0, stream>>>(ef, offs, eidx, out, N);
}

// Round 7
// 244.441 us; speedup vs baseline: 10.7634x; 1.0153x over previous
//
#include <hip/hip_runtime.h>
#include <math.h>
#include <stdint.h>

// Shapes (fixed by the reference)
// N=10000, E=100000, G=64, NB=16, EMB=16, S=8, COUT=16, LMAX=2
// WNUM = 3*16*8*8 = 3072 ; ef width = 16 + 48 + 144 = 208
// Per-edge compact result: m[48] (l*16+o) + n[3], stored as 52 floats.
//
// Main contraction as a fused GEMM via MFMA:
//   m[e][lo] = sum_ab o[e][ab] * ( sum_c h[e][c] * w3[c][lo*64+ab] ) + bias
// Per K-chunk u (= one ab), MFMA computes D = (h . B_ab) with h split into
// bf16 hi+lo (3 products, fp32 accum); then acc += o[e][ab] * D in exact f32.
// B-fragments are loaded DIRECTLY from global into registers (register double
// buffer, 1 chunk deep) -- no LDS staging, no barriers in the main loop; L1
// shares the 12KB/u across the block's 4 waves.

typedef float  f32x4  __attribute__((ext_vector_type(4)));
typedef short  s16x8  __attribute__((ext_vector_type(8)));
typedef __bf16 bf16x8 __attribute__((ext_vector_type(8)));

__device__ __forceinline__ float silu_f(float x) {
    return x / (1.0f + __expf(-x));
}

// split 8 f32 (two f32x4, k-local order j=0..7) into bf16 hi + lo fragments
__device__ __forceinline__ void split8(f32x4 a, f32x4 b, s16x8& hi, s16x8& lo) {
    bf16x8 h8, l8;
    #pragma unroll
    for (int i = 0; i < 4; ++i) {
        float z = a[i]; __bf16 zh = (__bf16)z; h8[i] = zh; l8[i] = (__bf16)(z - (float)zh);
        float y = b[i]; __bf16 yh = (__bf16)y; h8[4 + i] = yh; l8[4 + i] = (__bf16)(y - (float)yh);
    }
    hi = __builtin_bit_cast(s16x8, h8);
    lo = __builtin_bit_cast(s16x8, l8);
}

// ---------------- kernel 1 (fused setup): prep wz | node Ai | edge_dst hist ----------------
// K-step s (0..129): 32 k-values. s<128: ab=s>>1, c=(s&1)*32+kl. s>=128: ab=(s-128)*32+kl.
// Fragment lane l: col lo = t*16 + (l&15); kl = (l>>4)*8 + j.
// wz[ ((s*3 + t)*2 + plane)*512 + l*8 + j ]  (ushort bf16)
__global__ __launch_bounds__(256) void k_setup(const float* __restrict__ w3,
                                               const float* __restrict__ b3,
                                               ushort* __restrict__ wz,
                                               const int* __restrict__ A,
                                               const float* __restrict__ embt,
                                               const float* __restrict__ w1,
                                               const float* __restrict__ b1,
                                               const float* __restrict__ w2,
                                               const float* __restrict__ b2,
                                               float* __restrict__ Ai,
                                               const int* __restrict__ edst,
                                               int* __restrict__ deg,
                                               int N, int E, int aiB) {
    const int b = blockIdx.x;
    const int tid = threadIdx.x;
    if (b < 780) {                         // ---- prep: 780*256 = 199680 = 130*3*512
        int t = b * 256 + tid;
        int j    = t & 7;
        int l    = (t >> 3) & 63;
        int rest = t >> 9;          // s*3 + tt
        int tt   = rest % 3;
        int s    = rest / 3;
        int lo   = tt * 16 + (l & 15);
        int kl   = (l >> 4) * 8 + j;
        float v;
        if (s < 128) {
            int ab = s >> 1;
            int c  = (s & 1) * 32 + kl;
            v = w3[c * 3072 + lo * 64 + ab];
        } else {
            int ab = (s - 128) * 32 + kl;
            v = b3[lo * 64 + ab];
        }
        __bf16 hi  = (__bf16)v;
        __bf16 lor = (__bf16)(v - (float)hi);
        size_t base = (size_t)(s * 3 + tt) * 2 * 512 + l * 8 + j;
        wz[base]       = __builtin_bit_cast(ushort, hi);
        wz[base + 512] = __builtin_bit_cast(ushort, lor);
    } else if (b < 780 + aiB) {            // ---- node Ai
        int i = (b - 780) * 256 + tid;
        if (i >= N) return;
        float e[16];
        const float* er = embt + A[i] * 16;
        #pragma unroll
        for (int k = 0; k < 16; ++k) e[k] = er[k];
        float h1[64];
        #pragma unroll
        for (int j = 0; j < 64; ++j) {
            float a = b1[j];
            #pragma unroll
            for (int k = 0; k < 16; ++k) a = fmaf(e[k], w1[k * 64 + j], a);
            h1[j] = silu_f(a);
        }
        #pragma unroll
        for (int o = 0; o < 8; ++o) {
            float a = b2[o];
            #pragma unroll
            for (int j = 0; j < 64; ++j) a = fmaf(h1[j], w2[j * 8 + o], a);
            Ai[i * 8 + o] = a;
        }
    } else {                               // ---- histogram of edge_dst
        int e = (b - 780 - aiB) * 256 + tid;
        if (e < E) atomicAdd(&deg[edst[e]], 1);
    }
}

// ---------------- kernel 2: single-block exclusive scan (N=10000), 1024 threads ----------------
__global__ __launch_bounds__(1024) void k_scan(const int* __restrict__ deg,
                                               int* __restrict__ offs,
                                               int* __restrict__ cursor, int N) {
    __shared__ int part[1024];
    const int t = threadIdx.x;
    const int chunk = (N + 1023) / 1024;
    const int beg = t * chunk;
    const int end = min(beg + chunk, N);
    int s = 0;
    for (int i = beg; i < end; ++i) s += deg[i];
    part[t] = s;
    __syncthreads();
    for (int off = 1; off < 1024; off <<= 1) {
        int v = (t >= off) ? part[t - off] : 0;
        __syncthreads();
        part[t] += v;
        __syncthreads();
    }
    int run = (t == 0) ? 0 : part[t - 1];
    for (int i = beg; i < end; ++i) {
        offs[i] = run;
        cursor[i] = run;
        run += deg[i];
    }
    if (t == 1023) offs[N] = part[1023];
}

// ---------------- kernel 3: per-edge compute via MFMA ----------------
// Block = 256 threads = 4 waves = 128 edges (M=32 per wave: 2 x 16-row tiles).
// Front end (verified) runs twice (rows 0-63, 64-127); h moves to per-lane
// bf16 hi/lo fragments (registers). Main K-loop: BARRIER-FREE -- B fragments
// register-double-buffered straight from global (L1-shared across waves).
__global__ __launch_bounds__(256, 2) void k_edge(
    const float* __restrict__ pos, const int* __restrict__ batch,
    const int* __restrict__ esrc, const int* __restrict__ edst,
    const float* __restrict__ eshift, const float* __restrict__ cell,
    const float* __restrict__ fw1, const float* __restrict__ fb1,
    const float* __restrict__ fw2, const float* __restrict__ fb2,
    const ushort* __restrict__ wz,
    const float* __restrict__ Ai, float* __restrict__ ef,
    int* __restrict__ cursor, int* __restrict__ eidx, int E) {

    __shared__ __align__(16) float s_un[8704];   // h1 (stride 65) -> h (stride 68)
    __shared__ __align__(16) float s_o[8704];    // o[128 edges][68-stride]

    const int tid  = threadIdx.x;
    const int lane = tid & 63;
    const int w    = __builtin_amdgcn_readfirstlane(tid >> 6);   // wave id
    const int e0   = blockIdx.x * 128;
    const int j0   = w * 16;                                     // c-chunk

    const f32x4* wzv = reinterpret_cast<const f32x4*>(wz);

    // B-fragment load: 12 x 16B per lane, chunk U (perfectly coalesced, L1-shared)
    s16x8 Ba[12], Bb[12];
#define LOADB(ARR, U) { \
    const f32x4* gs = wzv + (size_t)(U) * 768 + lane; \
    _Pragma("unroll") \
    for (int f = 0; f < 12; ++f) ARR[f] = __builtin_bit_cast(s16x8, gs[f * 64]); }

    LOADB(Ba, 0);   // prologue: chunk 0 in flight across the whole front end

    // ---- front end, two rounds of 64 edges ----
    #pragma unroll
    for (int rr = 0; rr < 2; ++rr) {
        const int e = e0 + rr * 64 + lane;
        const bool valid = (e < E);
        const int ec = valid ? e : (E - 1);
        const int src = esrc[ec];
        const int dst = edst[ec];

        const int g0 = batch[src];
        const float s0 = eshift[ec * 3 + 0], s1 = eshift[ec * 3 + 1], s2 = eshift[ec * 3 + 2];
        const float* cl = cell + g0 * 9;
        float vx = pos[dst * 3 + 0] - pos[src * 3 + 0] + s0 * cl[0] + s1 * cl[3] + s2 * cl[6];
        float vy = pos[dst * 3 + 1] - pos[src * 3 + 1] + s0 * cl[1] + s1 * cl[4] + s2 * cl[7];
        float vz = pos[dst * 3 + 2] - pos[src * 3 + 2] + s0 * cl[2] + s1 * cl[5] + s2 * cl[8];
        float r = sqrtf(vx * vx + vy * vy + vz * vz);
        float rinv = 1.0f / fmaxf(r, 1e-9f);
        float nx = vx * rinv, ny = vy * rinv, nz = vz * rinv;

        float embv[16];
        const float step = 4.0f / 17.0f;
        const float sc = 4.0f / 1.12f;
        #pragma unroll
        for (int k = 0; k < 16; ++k) {
            float d = (r - (float)(k + 1) * step) / step;
            embv[k] = __expf(-d * d) * sc;
        }

        // h1 chunk -> s_un (stride 65)
        const int hb = (rr * 64 + lane) * 65;
        #pragma unroll
        for (int jj = 0; jj < 16; ++jj) {
            const int j = j0 + jj;
            float a = fb1[j];
            #pragma unroll
            for (int k = 0; k < 16; ++k) a = fmaf(embv[k], fw1[k * 64 + j], a);
            s_un[hb + j] = silu_f(a);
        }

        // o chunk -> s_o (stride 68)
        {
            const float* As = Ai + (size_t)src * 8;
            const float* Ad = Ai + (size_t)dst * 8;
            float fsa0 = As[2 * w], fsa1 = As[2 * w + 1];
            f32x4 d0 = *reinterpret_cast<const f32x4*>(Ad);
            f32x4 d1 = *reinterpret_cast<const f32x4*>(Ad + 4);
            float fdv[8] = {d0[0], d0[1], d0[2], d0[3], d1[0], d1[1], d1[2], d1[3]};
            const int ob = (rr * 64 + lane) * 68 + j0;
            #pragma unroll
            for (int i = 0; i < 8; ++i)  s_o[ob + i]     = fsa0 * fdv[i];
            #pragma unroll
            for (int i = 0; i < 8; ++i)  s_o[ob + 8 + i] = fsa1 * fdv[i];
        }

        // n + CSR scatter (one thread per edge)
        if (w == 0 && valid) {
            float* np = ef + (size_t)e * 52;
            np[48] = nx; np[49] = ny; np[50] = nz;
            int pp = atomicAdd(&cursor[dst], 1);
            eidx[pp] = e;
        }
    }
    __syncthreads();

    // ---- hc chunks (registers) for both rounds ----
    float hcr[2][16];
    #pragma unroll
    for (int rr = 0; rr < 2; ++rr) {
        const int hb = (rr * 64 + lane) * 65;
        #pragma unroll
        for (int i = 0; i < 16; ++i) hcr[rr][i] = fb2[j0 + i];
        #pragma unroll 4
        for (int j = 0; j < 64; ++j) {
            const float v = s_un[hb + j];
            const float* w2r = fw2 + j * 64 + j0;   // wave-uniform -> scalar
            #pragma unroll
            for (int i = 0; i < 16; ++i) hcr[rr][i] = fmaf(v, w2r[i], hcr[rr][i]);
        }
        #pragma unroll
        for (int i = 0; i < 16; ++i) hcr[rr][i] = silu_f(hcr[rr][i]);
    }
    __syncthreads();   // all h1 reads done -> rewrite region at stride 68

    #pragma unroll
    for (int rr = 0; rr < 2; ++rr) {
        const int hb = (rr * 64 + lane) * 68 + j0;
        #pragma unroll
        for (int i = 0; i < 16; ++i) s_un[hb + i] = hcr[rr][i];
    }
    __syncthreads();

    LOADB(Bb, 64);   // bias chunk in flight across fragment extraction

    // ---- extract per-lane A (h) and O (bias) fragments ----
    const int g = lane >> 4;                 // k-group
    const int mrow = w * 32 + (lane & 15);   // M-tile 0 row
    s16x8 AhF[2][2], AlF[2][2], OhF[2][2], OlF[2][2];
    #pragma unroll
    for (int mt = 0; mt < 2; ++mt) {
        const float* hr = s_un + (mrow + mt * 16) * 68;
        const float* orw = s_o + (mrow + mt * 16) * 68;
        f32x4 a0 = *reinterpret_cast<const f32x4*>(hr + g * 8);
        f32x4 a1 = *reinterpret_cast<const f32x4*>(hr + g * 8 + 4);
        split8(a0, a1, AhF[mt][0], AlF[mt][0]);
        f32x4 a2 = *reinterpret_cast<const f32x4*>(hr + 32 + g * 8);
        f32x4 a3 = *reinterpret_cast<const f32x4*>(hr + 32 + g * 8 + 4);
        split8(a2, a3, AhF[mt][1], AlF[mt][1]);
        f32x4 o0 = *reinterpret_cast<const f32x4*>(orw + g * 8);
        f32x4 o1 = *reinterpret_cast<const f32x4*>(orw + g * 8 + 4);
        split8(o0, o1, OhF[mt][0], OlF[mt][0]);
        f32x4 o2 = *reinterpret_cast<const f32x4*>(orw + 32 + g * 8);
        f32x4 o3 = *reinterpret_cast<const f32x4*>(orw + 32 + g * 8 + 4);
        split8(o2, o3, OhF[mt][1], OlF[mt][1]);
    }

    const int rb = w * 32 + (lane >> 4) * 4;   // first output row of this lane's D

    f32x4 acc[2][3];
    #pragma unroll
    for (int mt = 0; mt < 2; ++mt)
        #pragma unroll
        for (int t = 0; t < 3; ++t) acc[mt][t] = (f32x4){0.f, 0.f, 0.f, 0.f};

    // ---- bias tail FIRST (frees O-fragments before the main loop) ----
    __builtin_amdgcn_s_setprio(1);
    #pragma unroll
    for (int t = 0; t < 3; ++t) {
        #pragma unroll
        for (int sl = 0; sl < 2; ++sl) {
            s16x8 Bh = Bb[(sl * 3 + t) * 2];
            s16x8 Bl = Bb[(sl * 3 + t) * 2 + 1];
            acc[0][t] = __builtin_amdgcn_mfma_f32_16x16x32_bf16(OhF[0][sl], Bh, acc[0][t], 0, 0, 0);
            acc[0][t] = __builtin_amdgcn_mfma_f32_16x16x32_bf16(OhF[0][sl], Bl, acc[0][t], 0, 0, 0);
            acc[0][t] = __builtin_amdgcn_mfma_f32_16x16x32_bf16(OlF[0][sl], Bh, acc[0][t], 0, 0, 0);
            acc[1][t] = __builtin_amdgcn_mfma_f32_16x16x32_bf16(OhF[1][sl], Bh, acc[1][t], 0, 0, 0);
            acc[1][t] = __builtin_amdgcn_mfma_f32_16x16x32_bf16(OhF[1][sl], Bl, acc[1][t], 0, 0, 0);
            acc[1][t] = __builtin_amdgcn_mfma_f32_16x16x32_bf16(OlF[1][sl], Bh, acc[1][t], 0, 0, 0);
        }
    }
    __builtin_amdgcn_s_setprio(0);

    // ---- main K-loop: barrier-free, register double buffer, unroll x2 ----
#define MSTEP(BC, U) { \
    float ov[8]; \
    _Pragma("unroll") \
    for (int i = 0; i < 4; ++i) { \
        ov[i]     = s_o[(rb + i) * 68 + (U)]; \
        ov[4 + i] = s_o[(rb + 16 + i) * 68 + (U)]; \
    } \
    __builtin_amdgcn_s_setprio(1); \
    _Pragma("unroll") \
    for (int t = 0; t < 3; ++t) { \
        f32x4 D0 = {0.f, 0.f, 0.f, 0.f}; \
        f32x4 D1 = {0.f, 0.f, 0.f, 0.f}; \
        _Pragma("unroll") \
        for (int sl = 0; sl < 2; ++sl) { \
            s16x8 Bh = BC[(sl * 3 + t) * 2]; \
            s16x8 Bl = BC[(sl * 3 + t) * 2 + 1]; \
            D0 = __builtin_amdgcn_mfma_f32_16x16x32_bf16(AhF[0][sl], Bh, D0, 0, 0, 0); \
            D0 = __builtin_amdgcn_mfma_f32_16x16x32_bf16(AhF[0][sl], Bl, D0, 0, 0, 0); \
            D0 = __builtin_amdgcn_mfma_f32_16x16x32_bf16(AlF[0][sl], Bh, D0, 0, 0, 0); \
            D1 = __builtin_amdgcn_mfma_f32_16x16x32_bf16(AhF[1][sl], Bh, D1, 0, 0, 0); \
            D1 = __builtin_amdgcn_mfma_f32_16x16x32_bf16(AhF[1][sl], Bl, D1, 0, 0, 0); \
            D1 = __builtin_amdgcn_mfma_f32_16x16x32_bf16(AlF[1][sl], Bh, D1, 0, 0, 0); \
        } \
        __builtin_amdgcn_s_setprio(0); \
        _Pragma("unroll") \
        for (int i = 0; i < 4; ++i) { \
            acc[0][t][i] = fmaf(ov[i],     D0[i], acc[0][t][i]); \
            acc[1][t][i] = fmaf(ov[4 + i], D1[i], acc[1][t][i]); \
        } \
        __builtin_amdgcn_s_setprio(1); \
    } \
    __builtin_amdgcn_s_setprio(0); }

    for (int u = 0; u < 64; u += 2) {
        LOADB(Bb, u + 1);
        MSTEP(Ba, u);
        if (u + 2 < 64) LOADB(Ba, u + 2);
        MSTEP(Bb, u + 1);
    }
#undef MSTEP
#undef LOADB

    // ---- write m: D row = rb + i (edge), col = lane&15 (lo) ----
    #pragma unroll
    for (int mt = 0; mt < 2; ++mt) {
        #pragma unroll
        for (int t = 0; t < 3; ++t) {
            #pragma unroll
            for (int i = 0; i < 4; ++i) {
                const int ee = e0 + rb + mt * 16 + i;
                if (ee < E) ef[(size_t)ee * 52 + t * 16 + (lane & 15)] = acc[mt][t][i];
            }
        }
    }
}

// ---------------- kernel 4: gather-reduce per node ----------------
__global__ __launch_bounds__(256) void k_gather(const float* __restrict__ ef,
                                                const int* __restrict__ offs,
                                                const int* __restrict__ eidx,
                                                float* __restrict__ out, int N) {
    const int lane = threadIdx.x & 63;
    const int node = blockIdx.x * 4 + (threadIdx.x >> 6);
    if (node >= N) return;

    const int beg = offs[node];
    const int end = offs[node + 1];

    int mi[4], ii[4], jj[4], mode[4];
    #pragma unroll
    for (int t = 0; t < 4; ++t) {
        int c = lane + 64 * t;
        if (c < 16)       { mi[t] = c;                 ii[t] = 0;     jj[t] = 0;     mode[t] = 0; }
        else if (c < 64)  { int u = c - 16; mi[t] = 16 + u / 3; ii[t] = u % 3; jj[t] = 0; mode[t] = 1; }
        else if (c < 208) { int u = c - 64; mi[t] = 32 + u / 9; int rr = u % 9; ii[t] = rr / 3; jj[t] = rr % 3; mode[t] = 2; }
        else              { mi[t] = 0; ii[t] = 0; jj[t] = 0; mode[t] = 3; }
    }

    float acc[4] = {0.f, 0.f, 0.f, 0.f};
    for (int k = beg; k < end; ++k) {
        const int e = eidx[k];
        const float* b = ef + (size_t)e * 52;
        float v = (lane < 51) ? b[lane] : 0.0f;
        float n0 = __shfl(v, 48);
        float n1 = __shfl(v, 49);
        float n2 = __shfl(v, 50);
        #pragma unroll
        for (int t = 0; t < 4; ++t) {
            float mval = __shfl(v, mi[t]);
            float ni = (ii[t] == 0) ? n0 : ((ii[t] == 1) ? n1 : n2);
            float nj = (jj[t] == 0) ? n0 : ((jj[t] == 1) ? n1 : n2);
            float f  = (mode[t] == 0) ? 1.0f
                     : (mode[t] == 1) ? ni
                     : (mode[t] == 2) ? ni * nj
                     : 0.0f;
            acc[t] = fmaf(mval, f, acc[t]);
        }
    }

    const float inv = 1.0f / fmaxf((float)(end - beg), 1.0f);
    float* op = out + (size_t)node * 208;
    op[lane]        = acc[0] * inv;
    op[lane + 64]   = acc[1] * inv;
    op[lane + 128]  = acc[2] * inv;
    if (lane < 16) op[lane + 192] = acc[3] * inv;
}

extern "C" void kernel_launch(void* const* d_in, const int* in_sizes, int n_in,
                              void* d_out, int out_size, void* d_ws, size_t ws_size,
                              hipStream_t stream) {
    const float* pos    = (const float*)d_in[0];
    const int*   A      = (const int*)d_in[1];
    const int*   batch  = (const int*)d_in[2];
    const int*   esrc   = (const int*)d_in[3];
    const int*   edst   = (const int*)d_in[4];
    const float* eshift = (const float*)d_in[5];
    const float* cell   = (const float*)d_in[6];
    const float* embt   = (const float*)d_in[7];
    const float* mw1    = (const float*)d_in[8];
    const float* mb1    = (const float*)d_in[9];
    const float* mw2    = (const float*)d_in[10];
    const float* mb2    = (const float*)d_in[11];
    const float* fw1    = (const float*)d_in[12];
    const float* fb1    = (const float*)d_in[13];
    const float* fw2    = (const float*)d_in[14];
    const float* fb2    = (const float*)d_in[15];
    const float* w3     = (const float*)d_in[16];
    const float* b3     = (const float*)d_in[17];
    float* out = (float*)d_out;

    const int N = in_sizes[1];
    const int E = in_sizes[3];

    char* p = (char*)d_ws;
    auto take = [&](size_t bytes) {
        char* q = p;
        p += (bytes + 255) & ~(size_t)255;
        return q;
    };
    ushort* wz    = (ushort*)take((size_t)130 * 3 * 2 * 512 * sizeof(ushort)); // ~780 KiB
    float* Ai     = (float*)take((size_t)N * 8 * sizeof(float));
    int*   deg    = (int*)  take((size_t)N * sizeof(int));
    int*   offs   = (int*)  take((size_t)(N + 1) * sizeof(int));
    int*   cursor = (int*)  take((size_t)N * sizeof(int));
    int*   eidx   = (int*)  take((size_t)E * sizeof(int));
    float* ef     = (float*)take((size_t)E * 52 * sizeof(float)); // ~20.8 MiB

    hipMemsetAsync(deg, 0, (size_t)N * sizeof(int), stream);

    const int aiB = (N + 255) / 256;
    const int histB = (E + 255) / 256;
    k_setup<<<780 + aiB + histB, 256, 0, stream>>>(w3, b3, wz, A, embt, mw1, mb1,
                                                   mw2, mb2, Ai, edst, deg, N, E, aiB);
    k_scan<<<1, 1024, 0, stream>>>(deg, offs, cursor, N);
    k_edge<<<(E + 127) / 128, 256, 0, stream>>>(pos, batch, esrc, edst, eshift, cell,
                                                fw1, fb1, fw2, fb2, wz, Ai,
                                                ef, cursor, eidx, E);
    k_gather<<<(N + 3) / 4, 256, 0, stream>>>(ef, offs, eidx, out, N);
}